// Round 2
// baseline (316.453 us; speedup 1.0000x reference)
//
#include <hip/hip_runtime.h>
#include <hip/hip_bf16.h>

// Problem: B=4096, N=64, H=256 (all fixed). All inputs fp32, output fp32.
#define BATCH 4096
#define NMEM  64
#define HDIM  256
#define MROWS 320   // 256 W_w rows + 64 (h+w) rows

typedef __attribute__((ext_vector_type(8))) short short8;   // 8 bf16 = 4 VGPRs (MFMA A/B frag)
typedef __attribute__((ext_vector_type(4))) float floatx4;  // MFMA C/D frag

__device__ __forceinline__ float bf2f(unsigned short u) {
    union { unsigned int i; float f; } v; v.i = ((unsigned int)u) << 16; return v.f;
}
__device__ __forceinline__ unsigned short f2bf(float f) {
    union { float f; unsigned int i; } v; v.f = f;
    unsigned int x = v.i;
    return (unsigned short)((x + 0x7FFFu + ((x >> 16) & 1u)) >> 16);  // RNE
}

// ---------------------------------------------------------------------------
// Kernel 1: prep (fp32 inputs).
//  blocks 0..63   : block n computes A[n][k] = sum_h h[n,h]U[k,h] + w[n,h]V[k,h]
//                   (fp32 accumulate, store bf16) and M row (256+n) = bf16(h[n]+w[n])
//  blocks 64..127 : M rows 0..255 = bf16(W_w) (4 rows per block)
// ---------------------------------------------------------------------------
__global__ __launch_bounds__(256) void prep_kernel(
    const float* __restrict__ h,
    const float* __restrict__ w,
    const float* __restrict__ U_w,
    const float* __restrict__ V_w,
    const float* __restrict__ W_w,
    unsigned short* __restrict__ M,    // [320][256] bf16
    unsigned short* __restrict__ A)    // [64][256]  bf16
{
    const int bid = blockIdx.x;
    const int t   = threadIdx.x;
    if (bid < 64) {
        const int n = bid;
        __shared__ float h_lds[HDIM];
        __shared__ float w_lds[HDIM];
        h_lds[t] = h[n * HDIM + t];
        w_lds[t] = w[n * HDIM + t];
        __syncthreads();

        const float* Urow = U_w + t * HDIM;
        const float* Vrow = V_w + t * HDIM;
        float acc = 0.f;
        #pragma unroll 8
        for (int hh = 0; hh < HDIM; hh += 4) {
            float4 u = *(const float4*)(Urow + hh);
            float4 v = *(const float4*)(Vrow + hh);
            acc += h_lds[hh + 0] * u.x + h_lds[hh + 1] * u.y
                 + h_lds[hh + 2] * u.z + h_lds[hh + 3] * u.w;
            acc += w_lds[hh + 0] * v.x + w_lds[hh + 1] * v.y
                 + w_lds[hh + 2] * v.z + w_lds[hh + 3] * v.w;
        }
        A[n * HDIM + t] = f2bf(acc);
        M[(256 + n) * HDIM + t] = f2bf(h_lds[t] + w_lds[t]);
    } else {
        const int r0 = (bid - 64) * 4;
        #pragma unroll
        for (int r = 0; r < 4; ++r)
            M[(r0 + r) * HDIM + t] = f2bf(W_w[(r0 + r) * HDIM + t]);
    }
}

// ---------------------------------------------------------------------------
// Kernel 2: Call[b][j] = sum_h s_t[b,h] * M[j,h]   (bf16 MFMA, f32 out)
//   j in [0,256): C = s_t @ W_w^T ; j in [256,320): gate logits vs (h+w)
// grid = 256 blocks (one 16-row b-tile each), 4 waves/block, wave does 5 j-tiles.
// s_t is fp32; each element is read exactly once per block, so convert to bf16
// in-register while building the A fragments.
// Fragment layouts (m89/m120-verified):
//   A frag: lane l elem j -> A[m = l&15][k = (l>>4)*8 + j]
//   B frag: lane l elem j -> B[k = (l>>4)*8 + j][n = l&15]  (= M[j0+(l&15)][k], contiguous)
//   D     : lane l reg  r -> D[row = (l>>4)*4 + r][col = l&15]
// ---------------------------------------------------------------------------
__global__ __launch_bounds__(256) void gemm_kernel(
    const float* __restrict__ s_t,           // [4096][256] f32
    const unsigned short* __restrict__ M,    // [320][256]  bf16
    float* __restrict__ Call)                // [4096][320] f32
{
    const int b0   = blockIdx.x * 16;
    const int wave = threadIdx.x >> 6;
    const int lane = threadIdx.x & 63;
    const int m = lane & 15;
    const int q = lane >> 4;

    // Build all 8 K-step A-fragments (reused across the 5 j-tiles)
    const float* arow = s_t + (size_t)(b0 + m) * HDIM;
    short8 afrag[8];
    #pragma unroll
    for (int ks = 0; ks < 8; ++ks) {
        const int base = ks * 32 + q * 8;
        float4 f0 = *(const float4*)(arow + base);
        float4 f1 = *(const float4*)(arow + base + 4);
        short8 a;
        a[0] = (short)f2bf(f0.x); a[1] = (short)f2bf(f0.y);
        a[2] = (short)f2bf(f0.z); a[3] = (short)f2bf(f0.w);
        a[4] = (short)f2bf(f1.x); a[5] = (short)f2bf(f1.y);
        a[6] = (short)f2bf(f1.z); a[7] = (short)f2bf(f1.w);
        afrag[ks] = a;
    }

    #pragma unroll
    for (int jt = 0; jt < 5; ++jt) {
        const int j0 = (wave + jt * 4) * 16;
        const short8* brow = (const short8*)(M + (size_t)(j0 + m) * HDIM);
        floatx4 acc = {0.f, 0.f, 0.f, 0.f};
        #pragma unroll
        for (int ks = 0; ks < 8; ++ks) {
            short8 bfrag = brow[ks * 4 + q];
            acc = __builtin_amdgcn_mfma_f32_16x16x32_bf16(afrag[ks], bfrag, acc, 0, 0, 0);
        }
        #pragma unroll
        for (int r = 0; r < 4; ++r)
            Call[(size_t)(b0 + q * 4 + r) * MROWS + j0 + m] = acc[r];
    }
}

// ---------------------------------------------------------------------------
// Kernel 3: fused elementwise + row L2-normalize (fp32 out, 268 MB — the floor).
// grid = 512 blocks, each owns 8 consecutive b. LDS: A bf16 (32KB) + Call rows
// (8KB) + gates (2KB) = 42KB -> 3 blocks/CU. h (64KB f32) served from L1/L2.
// One wave per (b,n) row, 4 elems/lane, __shfl_xor reduction over 64 lanes.
// ---------------------------------------------------------------------------
__global__ __launch_bounds__(256) void fuse_kernel(
    const float* __restrict__ h,              // [64][256] f32
    const unsigned short* __restrict__ A,     // [64][256] bf16
    const float* __restrict__ Call,           // [4096][320] f32
    const float* __restrict__ prelu_a,        // [1] f32
    float* __restrict__ out)                  // [4096][64][256] f32
{
    __shared__ unsigned short A_lds[NMEM * HDIM];   // 32 KB
    __shared__ float C_lds[8 * HDIM];               // 8 KB
    __shared__ float g_lds[8 * NMEM];               // 2 KB

    const int t  = threadIdx.x;
    const int b0 = blockIdx.x * 8;
    const float pa = prelu_a[0];

    // stage A (16384 bf16 = 4096 ushort4)
    {
        const ushort4* As = (const ushort4*)A;
        ushort4* Ad = (ushort4*)A_lds;
        #pragma unroll
        for (int i = 0; i < 16; ++i)
            Ad[t + i * 256] = As[t + i * 256];
    }
    // stage Call first 256 cols for the 8 b's
    #pragma unroll
    for (int b = 0; b < 8; ++b)
        C_lds[b * HDIM + t] = Call[(size_t)(b0 + b) * MROWS + t];
    // gates: 8*64 = 512 sigmoids
    #pragma unroll
    for (int i = 0; i < 2; ++i) {
        int idx = t + i * 256;
        int b = idx >> 6, n = idx & 63;
        float x = Call[(size_t)(b0 + b) * MROWS + 256 + n];
        g_lds[idx] = 1.f / (1.f + __expf(-x));
    }
    __syncthreads();

    const int wave = t >> 6;
    const int lane = t & 63;
    const int k0 = lane * 4;

    for (int idx = wave; idx < 512; idx += 4) {
        const int b = idx >> 6, n = idx & 63;
        const float g = g_lds[idx];

        ushort4 av = *(const ushort4*)(A_lds + n * HDIM + k0);
        float4  hv = *(const float4*)(h + n * HDIM + k0);
        floatx4 cv = *(const floatx4*)(C_lds + b * HDIM + k0);

        float x0 = bf2f(av.x) + cv[0];
        float x1 = bf2f(av.y) + cv[1];
        float x2 = bf2f(av.z) + cv[2];
        float x3 = bf2f(av.w) + cv[3];
        x0 = (x0 >= 0.f) ? x0 : pa * x0;
        x1 = (x1 >= 0.f) ? x1 : pa * x1;
        x2 = (x2 >= 0.f) ? x2 : pa * x2;
        x3 = (x3 >= 0.f) ? x3 : pa * x3;
        float y0 = hv.x + g * x0;
        float y1 = hv.y + g * x1;
        float y2 = hv.z + g * x2;
        float y3 = hv.w + g * x3;

        float ss = y0 * y0 + y1 * y1 + y2 * y2 + y3 * y3;
        #pragma unroll
        for (int off = 1; off < 64; off <<= 1)
            ss += __shfl_xor(ss, off);
        const float rn = rsqrtf(ss);

        float4 ov;
        ov.x = y0 * rn;
        ov.y = y1 * rn;
        ov.z = y2 * rn;
        ov.w = y3 * rn;
        *(float4*)(out + ((size_t)(b0 + b) * NMEM + n) * HDIM + k0) = ov;
    }
}

// ---------------------------------------------------------------------------
extern "C" void kernel_launch(void* const* d_in, const int* in_sizes, int n_in,
                              void* d_out, int out_size, void* d_ws, size_t ws_size,
                              hipStream_t stream) {
    const float* s_t     = (const float*)d_in[0];
    const float* h       = (const float*)d_in[1];
    const float* w       = (const float*)d_in[2];
    const float* U_w     = (const float*)d_in[3];
    const float* V_w     = (const float*)d_in[4];
    const float* W_w     = (const float*)d_in[5];
    const float* prelu_a = (const float*)d_in[6];
    float* out = (float*)d_out;

    // ws layout: M bf16 [320][256] (160KB) | A bf16 [64][256] (32KB) | Call f32 [4096][320] (5.24MB)
    unsigned short* M = (unsigned short*)d_ws;
    unsigned short* A = (unsigned short*)((char*)d_ws + MROWS * HDIM * 2);
    float* Call = (float*)((char*)d_ws + MROWS * HDIM * 2 + NMEM * HDIM * 2);

    prep_kernel<<<128, 256, 0, stream>>>(h, w, U_w, V_w, W_w, M, A);
    gemm_kernel<<<BATCH / 16, 256, 0, stream>>>(s_t, M, Call);
    fuse_kernel<<<BATCH / 8, 256, 0, stream>>>(h, A, Call, prelu_a, out);
}

// Round 3
// 305.849 us; speedup vs baseline: 1.0347x; 1.0347x over previous
//
#include <hip/hip_runtime.h>
#include <hip/hip_bf16.h>

// Problem: B=4096, N=64, H=256 (all fixed). All inputs fp32, output fp32.
#define BATCH 4096
#define NMEM  64
#define HDIM  256
#define MROWS 320   // 256 W_w rows + 64 (h+w) rows

typedef __attribute__((ext_vector_type(8))) short short8;   // 8 bf16 = 4 VGPRs (MFMA A/B frag)
typedef __attribute__((ext_vector_type(4))) float floatx4;  // MFMA C/D frag

__device__ __forceinline__ float bf2f(unsigned short u) {
    union { unsigned int i; float f; } v; v.i = ((unsigned int)u) << 16; return v.f;
}
__device__ __forceinline__ unsigned short f2bf(float f) {
    union { float f; unsigned int i; } v; v.f = f;
    unsigned int x = v.i;
    return (unsigned short)((x + 0x7FFFu + ((x >> 16) & 1u)) >> 16);  // RNE
}
__device__ __forceinline__ short8 pack_bf16x8(float4 f0, float4 f1) {
    short8 a;
    a[0] = (short)f2bf(f0.x); a[1] = (short)f2bf(f0.y);
    a[2] = (short)f2bf(f0.z); a[3] = (short)f2bf(f0.w);
    a[4] = (short)f2bf(f1.x); a[5] = (short)f2bf(f1.y);
    a[6] = (short)f2bf(f1.z); a[7] = (short)f2bf(f1.w);
    return a;
}

// ---------------------------------------------------------------------------
// Kernel 1: prep v2.
//  blocks 0..15 : A = [h|w] @ [U|V]^T via MFMA (K=512). Block j -> cols
//                 j*16..+15; wave w -> rows w*16..+15. Same fragment
//                 conventions as gemm_kernel (validated in R2).
//  blocks 16..31: M rows, 20 rows/block, coalesced:
//                 M[r] = bf16(W_w[r]) for r<256, else bf16(h[r-256]+w[r-256]).
// ---------------------------------------------------------------------------
__global__ __launch_bounds__(256) void prep_kernel(
    const float* __restrict__ h,
    const float* __restrict__ w,
    const float* __restrict__ U_w,
    const float* __restrict__ V_w,
    const float* __restrict__ W_w,
    unsigned short* __restrict__ M,    // [320][256] bf16
    unsigned short* __restrict__ A)    // [64][256]  bf16
{
    const int bid = blockIdx.x;
    const int t   = threadIdx.x;
    if (bid < 16) {
        const int wv   = t >> 6;
        const int lane = t & 63;
        const int m = lane & 15;
        const int q = lane >> 4;
        const int j0 = bid * 16;

        const float* ah = h   + (size_t)(wv * 16 + m) * HDIM;  // row n of h
        const float* aw = w   + (size_t)(wv * 16 + m) * HDIM;  // row n of w
        const float* bu = U_w + (size_t)(j0 + m) * HDIM;       // row k of U
        const float* bv = V_w + (size_t)(j0 + m) * HDIM;       // row k of V

        floatx4 acc = {0.f, 0.f, 0.f, 0.f};
        #pragma unroll
        for (int ks = 0; ks < 16; ++ks) {
            const float* asrc = (ks < 8) ? ah : aw;
            const float* bsrc = (ks < 8) ? bu : bv;
            const int off = (ks & 7) * 32 + q * 8;
            float4 a0 = *(const float4*)(asrc + off);
            float4 a1 = *(const float4*)(asrc + off + 4);
            float4 b0 = *(const float4*)(bsrc + off);
            float4 b1 = *(const float4*)(bsrc + off + 4);
            acc = __builtin_amdgcn_mfma_f32_16x16x32_bf16(
                pack_bf16x8(a0, a1), pack_bf16x8(b0, b1), acc, 0, 0, 0);
        }
        // D: lane l reg r -> row q*4+r (n = wv*16+q*4+r), col m (k = j0+m)
        #pragma unroll
        for (int r = 0; r < 4; ++r)
            A[(size_t)(wv * 16 + q * 4 + r) * HDIM + j0 + m] = f2bf(acc[r]);
    } else {
        const int r0 = (bid - 16) * 20;
        for (int rr = 0; rr < 20; ++rr) {
            const int r = r0 + rr;
            float v;
            if (r < 256) v = W_w[(size_t)r * HDIM + t];
            else         v = h[(size_t)(r - 256) * HDIM + t] + w[(size_t)(r - 256) * HDIM + t];
            M[(size_t)r * HDIM + t] = f2bf(v);
        }
    }
}

// ---------------------------------------------------------------------------
// Kernel 2: Call[b][j] = sum_h s_t[b,h] * M[j,h]   (bf16 MFMA, f32 out)
//   j in [0,256): C = s_t @ W_w^T ; j in [256,320): gate logits vs (h+w)
// grid = 256 blocks (one 16-row b-tile each), 4 waves/block, wave does 5 j-tiles.
// Fragment layouts (m89/m120-verified; validated by R2 pass):
//   A frag: lane l elem j -> A[m = l&15][k = (l>>4)*8 + j]
//   B frag: lane l elem j -> B[k = (l>>4)*8 + j][n = l&15]
//   D     : lane l reg  r -> D[row = (l>>4)*4 + r][col = l&15]
// ---------------------------------------------------------------------------
__global__ __launch_bounds__(256) void gemm_kernel(
    const float* __restrict__ s_t,           // [4096][256] f32
    const unsigned short* __restrict__ M,    // [320][256]  bf16
    float* __restrict__ Call)                // [4096][320] f32
{
    const int b0   = blockIdx.x * 16;
    const int wave = threadIdx.x >> 6;
    const int lane = threadIdx.x & 63;
    const int m = lane & 15;
    const int q = lane >> 4;

    const float* arow = s_t + (size_t)(b0 + m) * HDIM;
    short8 afrag[8];
    #pragma unroll
    for (int ks = 0; ks < 8; ++ks) {
        const int base = ks * 32 + q * 8;
        afrag[ks] = pack_bf16x8(*(const float4*)(arow + base),
                                *(const float4*)(arow + base + 4));
    }

    #pragma unroll
    for (int jt = 0; jt < 5; ++jt) {
        const int j0 = (wave + jt * 4) * 16;
        const short8* brow = (const short8*)(M + (size_t)(j0 + m) * HDIM);
        floatx4 acc = {0.f, 0.f, 0.f, 0.f};
        #pragma unroll
        for (int ks = 0; ks < 8; ++ks) {
            short8 bfrag = brow[ks * 4 + q];
            acc = __builtin_amdgcn_mfma_f32_16x16x32_bf16(afrag[ks], bfrag, acc, 0, 0, 0);
        }
        #pragma unroll
        for (int r = 0; r < 4; ++r)
            Call[(size_t)(b0 + q * 4 + r) * MROWS + j0 + m] = acc[r];
    }
}

// ---------------------------------------------------------------------------
// Kernel 3: fuse v2 — elementwise + row L2-normalize.
// One block per b (4096 blocks, 256 thr, ~1.3 KB LDS -> occupancy-unbound).
// Quarter-wave (16 lanes) per row, 16 elems/lane: reduction is only 4
// __shfl_xor steps; 4 rows/wave/iter x 4 unrolled iters overlap the chains.
// Lane lq covers cols {lq*4 + j*64}, j=0..3:
//   - C_lds reads: all 4 quarters read identical addrs -> LDS broadcast
//   - h/A/out: 16-lane x 16 B = 256 B contiguous segments (coalesced)
// ---------------------------------------------------------------------------
__global__ __launch_bounds__(256) void fuse_kernel(
    const float* __restrict__ h,              // [64][256] f32
    const unsigned short* __restrict__ A,     // [64][256] bf16
    const float* __restrict__ Call,           // [4096][320] f32
    const float* __restrict__ prelu_a,        // [1] f32
    float* __restrict__ out)                  // [4096][64][256] f32
{
    __shared__ float C_lds[HDIM];   // 1 KB
    __shared__ float g_lds[NMEM];   // 256 B

    const int t = threadIdx.x;
    const int b = blockIdx.x;
    const float pa = prelu_a[0];

    C_lds[t] = Call[(size_t)b * MROWS + t];
    if (t < NMEM) {
        float x = Call[(size_t)b * MROWS + 256 + t];
        g_lds[t] = 1.f / (1.f + __expf(-x));
    }
    __syncthreads();

    const int wave = t >> 6;
    const int lane = t & 63;
    const int qw   = lane >> 4;   // quarter id 0..3
    const int lq   = lane & 15;   // lane within quarter

    #pragma unroll
    for (int i = 0; i < 4; ++i) {
        const int n = i * 16 + wave * 4 + qw;   // covers 0..63 exactly once
        const float g = g_lds[n];
        const float* hrow = h + (size_t)n * HDIM;
        const unsigned short* Arow = A + (size_t)n * HDIM;

        float y[16];
        float ss = 0.f;
        #pragma unroll
        for (int j = 0; j < 4; ++j) {
            const int k = lq * 4 + j * 64;
            float4  hv = *(const float4*)(hrow + k);
            ushort4 av = *(const ushort4*)(Arow + k);
            float4  cv = *(const float4*)(&C_lds[k]);
            float x0 = bf2f(av.x) + cv.x;
            float x1 = bf2f(av.y) + cv.y;
            float x2 = bf2f(av.z) + cv.z;
            float x3 = bf2f(av.w) + cv.w;
            x0 = (x0 >= 0.f) ? x0 : pa * x0;
            x1 = (x1 >= 0.f) ? x1 : pa * x1;
            x2 = (x2 >= 0.f) ? x2 : pa * x2;
            x3 = (x3 >= 0.f) ? x3 : pa * x3;
            float y0 = hv.x + g * x0;
            float y1 = hv.y + g * x1;
            float y2 = hv.z + g * x2;
            float y3 = hv.w + g * x3;
            y[j * 4 + 0] = y0; y[j * 4 + 1] = y1;
            y[j * 4 + 2] = y2; y[j * 4 + 3] = y3;
            ss += y0 * y0 + y1 * y1 + y2 * y2 + y3 * y3;
        }
        // reduce across the 16-lane quarter (xor offsets stay in-quarter)
        ss += __shfl_xor(ss, 1);
        ss += __shfl_xor(ss, 2);
        ss += __shfl_xor(ss, 4);
        ss += __shfl_xor(ss, 8);
        const float rn = rsqrtf(ss);

        float* orow = out + ((size_t)b * NMEM + n) * HDIM;
        #pragma unroll
        for (int j = 0; j < 4; ++j) {
            const int k = lq * 4 + j * 64;
            float4 ov;
            ov.x = y[j * 4 + 0] * rn;
            ov.y = y[j * 4 + 1] * rn;
            ov.z = y[j * 4 + 2] * rn;
            ov.w = y[j * 4 + 3] * rn;
            *(float4*)(orow + k) = ov;
        }
    }
}

// ---------------------------------------------------------------------------
extern "C" void kernel_launch(void* const* d_in, const int* in_sizes, int n_in,
                              void* d_out, int out_size, void* d_ws, size_t ws_size,
                              hipStream_t stream) {
    const float* s_t     = (const float*)d_in[0];
    const float* h       = (const float*)d_in[1];
    const float* w       = (const float*)d_in[2];
    const float* U_w     = (const float*)d_in[3];
    const float* V_w     = (const float*)d_in[4];
    const float* W_w     = (const float*)d_in[5];
    const float* prelu_a = (const float*)d_in[6];
    float* out = (float*)d_out;

    // ws layout: M bf16 [320][256] (160KB) | A bf16 [64][256] (32KB) | Call f32 [4096][320] (5.24MB)
    unsigned short* M = (unsigned short*)d_ws;
    unsigned short* A = (unsigned short*)((char*)d_ws + MROWS * HDIM * 2);
    float* Call = (float*)((char*)d_ws + MROWS * HDIM * 2 + NMEM * HDIM * 2);

    prep_kernel<<<32, 256, 0, stream>>>(h, w, U_w, V_w, W_w, M, A);
    gemm_kernel<<<BATCH / 16, 256, 0, stream>>>(s_t, M, Call);
    fuse_kernel<<<BATCH, 256, 0, stream>>>(h, A, Call, prelu_a, out);
}